// Round 17
// baseline (242.662 us; speedup 1.0000x reference)
//
#include <hip/hip_runtime.h>
#include <hip/hip_bf16.h>

#define B_ 2
#define S_ 2048
#define H_ 2048
#define NH_ 16
#define HD_ 64
#define DQ_ 2048   // 2*NH*HD
#define DV_ 1024   // NH*HD
#define QKS_ 4096  // fused QK row stride

using bf16x8 = __attribute__((ext_vector_type(8))) __bf16;
using f32x4  = __attribute__((ext_vector_type(4))) float;

typedef __attribute__((address_space(1))) unsigned int u32g;
typedef __attribute__((address_space(3))) unsigned int u32l;

__device__ __forceinline__ void gload_lds16(const __bf16* g, __bf16* l) {
  __builtin_amdgcn_global_load_lds((u32g*)g, (u32l*)l, 16, 0, 0);
}

// XOR-swizzle, 256B rows (16 chunks of 16B): involution, write+read identical.
__device__ __forceinline__ int swz(int row, int colb, int strideB) {
  return row * strideB + (colb ^ (((row ^ (row >> 3)) & 7) << 4));
}
__device__ __forceinline__ int fxor(int row) { return (row ^ (row >> 3)) & 7; }

__device__ __forceinline__ unsigned int pk2(float a, float b) {
  __bf16 ba = (__bf16)a, bb = (__bf16)b;
  unsigned short ua, ub;
  __builtin_memcpy(&ua, &ba, 2);
  __builtin_memcpy(&ub, &bb, 2);
  return (unsigned int)ua | ((unsigned int)ub << 16);
}

// ---------------- prep kernels ----------------

__global__ __launch_bounds__(256) void cast_hidden(const float* __restrict__ in,
                                                   __bf16* __restrict__ out, int n) {
  int i = (blockIdx.x * 256 + threadIdx.x) * 8;
  if (i >= n) return;
  float4 a = *reinterpret_cast<const float4*>(in + i);
  float4 b = *reinterpret_cast<const float4*>(in + i + 4);
  bf16x8 o;
  o[0] = (__bf16)a.x; o[1] = (__bf16)a.y; o[2] = (__bf16)a.z; o[3] = (__bf16)a.w;
  o[4] = (__bf16)b.x; o[5] = (__bf16)b.y; o[6] = (__bf16)b.z; o[7] = (__bf16)b.w;
  *reinterpret_cast<bf16x8*>(out + i) = o;
}

// in: R x C f32 row-major  ->  out: C x R bf16 row-major
__global__ __launch_bounds__(256) void transpose_cast(const float* __restrict__ in,
                                                      __bf16* __restrict__ out, int R, int C) {
  __shared__ float tile[32][33];
  int tx = threadIdx.x & 31, ty = threadIdx.x >> 5;
  int c0 = blockIdx.x * 32, r0 = blockIdx.y * 32;
  for (int i = 0; i < 32; i += 8)
    tile[ty + i][tx] = in[(size_t)(r0 + ty + i) * C + c0 + tx];
  __syncthreads();
  for (int i = 0; i < 32; i += 8)
    out[(size_t)(c0 + ty + i) * R + r0 + tx] = (__bf16)tile[tx][ty + i];
}

// dual transpose (z selects job): one launch for Wq+Wk
__global__ __launch_bounds__(256) void transpose_cast2(const float* __restrict__ in0,
                                                       __bf16* __restrict__ out0,
                                                       const float* __restrict__ in1,
                                                       __bf16* __restrict__ out1,
                                                       int R, int C) {
  __shared__ float tile[32][33];
  const float* in = blockIdx.z ? in1 : in0;
  __bf16* out = blockIdx.z ? out1 : out0;
  int tx = threadIdx.x & 31, ty = threadIdx.x >> 5;
  int c0 = blockIdx.x * 32, r0 = blockIdx.y * 32;
  for (int i = 0; i < 32; i += 8)
    tile[ty + i][tx] = in[(size_t)(r0 + ty + i) * C + c0 + tx];
  __syncthreads();
  for (int i = 0; i < 32; i += 8)
    out[(size_t)(c0 + ty + i) * R + r0 + tx] = (__bf16)tile[tx][ty + i];
}

// ------- GEMM: C[M][N] = A[M][K] * Bt[N][K]^T, 2-deep counted-vmcnt pipeline ----
// (V GEMM: 128x128 tile keeps its grid full-width)

template <typename OutT>
__global__ __launch_bounds__(256) void gemm_bt(const __bf16* __restrict__ A,
                                               const __bf16* __restrict__ Bt,
                                               OutT* __restrict__ C,
                                               int M, int N, int K) {
  __shared__ __bf16 As[2][128 * 32];
  __shared__ __bf16 Bs[2][128 * 32];
  const int nx = gridDim.x;
  int id = blockIdx.y * nx + blockIdx.x;
  const int cpx = (nx * gridDim.y) >> 3;
  id = (id & 7) * cpx + (id >> 3);
  const int bm = id / nx, bn = id % nx;

  const int tid = threadIdx.x;
  const int wid = tid >> 6, lane = tid & 63;
  const int wm = wid >> 1, wn = wid & 1;
  const int g = lane >> 4, c = lane & 15;

  f32x4 acc[4][4] = {};
  const __bf16* Abase = A + (size_t)(bm * 128) * K;
  const __bf16* Bbase = Bt + (size_t)(bn * 128) * K;
  const int srow = wid * 16 + (lane >> 2);
  const int scol = (lane & 3) * 8;
  const int nk = K >> 5;

  auto stage = [&](int p, int kt) {
    int k0 = kt * 32;
    gload_lds16(Abase + (size_t)srow * K + k0 + scol,        &As[p][(wid * 16) * 32]);
    gload_lds16(Abase + (size_t)(srow + 64) * K + k0 + scol, &As[p][(64 + wid * 16) * 32]);
    gload_lds16(Bbase + (size_t)srow * K + k0 + scol,        &Bs[p][(wid * 16) * 32]);
    gload_lds16(Bbase + (size_t)(srow + 64) * K + k0 + scol, &Bs[p][(64 + wid * 16) * 32]);
  };

  stage(0, 0);
  stage(1, 1);

  for (int kt = 0; kt < nk; ++kt) {
    const int p = kt & 1;
    if (kt + 1 < nk) {
      asm volatile("s_waitcnt vmcnt(4)" ::: "memory");
    } else {
      asm volatile("s_waitcnt vmcnt(0)" ::: "memory");
    }
    __builtin_amdgcn_s_barrier();
    __builtin_amdgcn_sched_barrier(0);

    bf16x8 af[4], bfv[4];
#pragma unroll
    for (int i = 0; i < 4; ++i)
      af[i] = *reinterpret_cast<const bf16x8*>(&As[p][(wm * 64 + i * 16 + c) * 32 + g * 8]);
#pragma unroll
    for (int i = 0; i < 4; ++i)
      bfv[i] = *reinterpret_cast<const bf16x8*>(&Bs[p][(wn * 64 + i * 16 + c) * 32 + g * 8]);
#pragma unroll
    for (int m = 0; m < 4; ++m)
#pragma unroll
      for (int n = 0; n < 4; ++n)
        acc[m][n] = __builtin_amdgcn_mfma_f32_16x16x32_bf16(af[m], bfv[n], acc[m][n], 0, 0, 0);

    __builtin_amdgcn_sched_barrier(0);
    __builtin_amdgcn_s_barrier();
    if (kt + 2 < nk) stage(p, kt + 2);
  }

#pragma unroll
  for (int m = 0; m < 4; ++m)
#pragma unroll
    for (int n = 0; n < 4; ++n)
#pragma unroll
      for (int r = 0; r < 4; ++r) {
        int row = bm * 128 + wm * 64 + m * 16 + g * 4 + r;
        int col = bn * 128 + wn * 64 + n * 16 + c;
        float v = acc[m][n][r];
        if constexpr (sizeof(OutT) == 2)
          C[(size_t)row * N + col] = (OutT)(__bf16)v;
        else
          C[(size_t)row * N + col] = v;
      }
}

// ---- GEMM 256x256, 8 waves, BK=64, 8-phase counted-vmcnt schedule ----
// (verified R11; R17: also used for O GEMM, 128-block grid = single round)

template <typename OutT>
__global__ __launch_bounds__(512, 2) void gemm256(const __bf16* __restrict__ A,
                                                  const __bf16* __restrict__ Bt,
                                                  OutT* __restrict__ C,
                                                  int M, int N, int K) {
  __shared__ __bf16 As[2][256 * 64];
  __shared__ __bf16 Bs[2][256 * 64];
  const int nx = gridDim.x;
  int id = blockIdx.y * nx + blockIdx.x;
  const int cpx = (nx * gridDim.y) >> 3;
  id = (id & 7) * cpx + (id >> 3);
  const int bm = id / nx, bn = id % nx;

  const int tid = threadIdx.x;
  const int wid = tid >> 6, lane = tid & 63;
  const int wm = wid >> 2, wn = wid & 3;
  const int g = lane >> 4, c = lane & 15;

  f32x4 acc[8][4] = {};
  bf16x8 af[4][2];
  bf16x8 bfv[4][2];
  const __bf16* Abase = A + (size_t)(bm * 256) * K;
  const __bf16* Bbase = Bt + (size_t)(bn * 256) * K;
  const int niter = K >> 7;

  auto stageA = [&](int p, int half, int kt) {
#pragma unroll
    for (int j = 0; j < 2; ++j) {
      int row = half * 128 + j * 64 + wid * 8 + (lane >> 3);
      int gc = (lane & 7) ^ (row & 7);
      gload_lds16(Abase + (size_t)row * K + kt * 64 + gc * 8,
                  &As[p][(half * 128 + j * 64 + wid * 8) * 64]);
    }
  };
  auto stageB = [&](int p, int half, int kt) {
#pragma unroll
    for (int j = 0; j < 2; ++j) {
      int row = half * 128 + j * 64 + wid * 8 + (lane >> 3);
      int gc = (lane & 7) ^ (row & 7);
      gload_lds16(Bbase + (size_t)row * K + kt * 64 + gc * 8,
                  &Bs[p][(half * 128 + j * 64 + wid * 8) * 64]);
    }
  };
  auto readA = [&](int p, int m, int kk) -> bf16x8 {
    int row = wm * 128 + m * 16 + c;
    int ch = (kk * 4 + g) ^ (row & 7);
    return *reinterpret_cast<const bf16x8*>(&As[p][row * 64 + ch * 8]);
  };
  auto readB = [&](int p, int n, int kk) -> bf16x8 {
    int row = wn * 64 + n * 16 + c;
    int ch = (kk * 4 + g) ^ (row & 7);
    return *reinterpret_cast<const bf16x8*>(&Bs[p][row * 64 + ch * 8]);
  };
  auto quad = [&](int mb, int nb) {
    __builtin_amdgcn_s_setprio(1);
#pragma unroll
    for (int mi = 0; mi < 4; ++mi)
#pragma unroll
      for (int ni = 0; ni < 2; ++ni)
#pragma unroll
        for (int kk = 0; kk < 2; ++kk)
          acc[mb + mi][nb + ni] = __builtin_amdgcn_mfma_f32_16x16x32_bf16(
              af[mi][kk], bfv[nb + ni][kk], acc[mb + mi][nb + ni], 0, 0, 0);
    __builtin_amdgcn_s_setprio(0);
  };
#define BAR1_LGKM()  __builtin_amdgcn_s_barrier(); \
    asm volatile("s_waitcnt lgkmcnt(0)" ::: "memory"); \
    __builtin_amdgcn_sched_barrier(0)
#define BAR2()  __builtin_amdgcn_sched_barrier(0); __builtin_amdgcn_s_barrier()

  stageA(0, 0, 0); stageA(0, 1, 0);
  stageB(0, 0, 0); stageB(0, 1, 0);
  stageB(1, 0, 1); stageB(1, 1, 1);
  asm volatile("s_waitcnt vmcnt(0)" ::: "memory");
  __builtin_amdgcn_s_barrier();

  for (int i = 0; i < niter; ++i) {
    const int t1 = 2 * i + 1;
    const bool more = (i + 1 < niter);
    // ph1
#pragma unroll
    for (int mi = 0; mi < 4; ++mi) { af[mi][0] = readA(0, mi, 0); af[mi][1] = readA(0, mi, 1); }
#pragma unroll
    for (int ni = 0; ni < 2; ++ni) { bfv[ni][0] = readB(0, ni, 0); bfv[ni][1] = readB(0, ni, 1); }
    stageA(1, 0, t1);
    BAR1_LGKM(); quad(0, 0); BAR2();
    // ph2
#pragma unroll
    for (int ni = 2; ni < 4; ++ni) { bfv[ni][0] = readB(0, ni, 0); bfv[ni][1] = readB(0, ni, 1); }
    stageA(1, 1, t1);
    BAR1_LGKM(); quad(0, 2); BAR2();
    // ph3
#pragma unroll
    for (int mi = 0; mi < 4; ++mi) { af[mi][0] = readA(0, 4 + mi, 0); af[mi][1] = readA(0, 4 + mi, 1); }
    if (more) stageB(0, 0, t1 + 1);
    BAR1_LGKM(); quad(4, 0); BAR2();
    // ph4
    if (more) {
      stageB(0, 1, t1 + 1);
      asm volatile("s_waitcnt vmcnt(4)" ::: "memory");
    } else {
      asm volatile("s_waitcnt vmcnt(0)" ::: "memory");
    }
    __builtin_amdgcn_s_barrier();
    __builtin_amdgcn_sched_barrier(0);
    quad(4, 2); BAR2();
    // ph5
#pragma unroll
    for (int mi = 0; mi < 4; ++mi) { af[mi][0] = readA(1, mi, 0); af[mi][1] = readA(1, mi, 1); }
#pragma unroll
    for (int ni = 0; ni < 2; ++ni) { bfv[ni][0] = readB(1, ni, 0); bfv[ni][1] = readB(1, ni, 1); }
    if (more) stageA(0, 0, t1 + 1);
    BAR1_LGKM(); quad(0, 0); BAR2();
    // ph6
#pragma unroll
    for (int ni = 2; ni < 4; ++ni) { bfv[ni][0] = readB(1, ni, 0); bfv[ni][1] = readB(1, ni, 1); }
    if (more) stageA(0, 1, t1 + 1);
    BAR1_LGKM(); quad(0, 2); BAR2();
    // ph7
#pragma unroll
    for (int mi = 0; mi < 4; ++mi) { af[mi][0] = readA(1, 4 + mi, 0); af[mi][1] = readA(1, 4 + mi, 1); }
    if (more) stageB(1, 0, t1 + 2);
    BAR1_LGKM(); quad(4, 0); BAR2();
    // ph8
    if (more) {
      stageB(1, 1, t1 + 2);
      asm volatile("s_waitcnt vmcnt(4)" ::: "memory");
    } else {
      asm volatile("s_waitcnt vmcnt(0)" ::: "memory");
    }
    __builtin_amdgcn_s_barrier();
    __builtin_amdgcn_sched_barrier(0);
    quad(4, 2); BAR2();
  }
#undef BAR1_LGKM
#undef BAR2

#pragma unroll
  for (int m = 0; m < 8; ++m)
#pragma unroll
    for (int n = 0; n < 4; ++n)
#pragma unroll
      for (int r = 0; r < 4; ++r) {
        int row = bm * 256 + wm * 128 + m * 16 + g * 4 + r;
        int col = bn * 256 + wn * 64 + n * 16 + c;
        float v = acc[m][n][r];
        if constexpr (sizeof(OutT) == 2)
          C[(size_t)row * N + col] = (OutT)(__bf16)v;
        else
          C[(size_t)row * N + col] = v;
      }
}

// ------------- differential flash attention: swapped-QK, P in registers -----------
// (R16 measured-best, 80 us: S^T=mfma(kf,qf), lane-local softmax, V-frag hoist,
// ones-MFMA rowsum, pk2+shfl P^T redistribution, O^T partials, KV-split +
// bit4-complement qt. UNCHANGED this round.)

__global__ __launch_bounds__(256, 2) void diffattn(const __bf16* __restrict__ QK,
                                                   const __bf16* __restrict__ V,
                                                   __bf16* __restrict__ OpA,
                                                   __bf16* __restrict__ OpB,
                                                   float* __restrict__ ml,
                                                   const float* __restrict__ lambda_param) {
  __shared__ __bf16 Ks[2][64 * 128];   // [kv][d] swizzled, 2x16KB
  __shared__ __bf16 Vs[2][64 * 64];    // [d][kv] (V^T) swizzled, 2x8KB

  const int y = blockIdx.y;
  const int qt = ((y >> 4) & 1) ? blockIdx.x : (gridDim.x - 1 - blockIdx.x);
  const int bh = y >> 1;
  const int half = y & 1;
  const int b = bh >> 4, h = bh & 15;
  const int tid = threadIdx.x;
  const int w = tid >> 6, lane = tid & 63;
  const int g = lane >> 4, c = lane & 15;
  const float NEG_INF = -__builtin_inff();

  const int srcA = c + 32 * (g & 1);
  const int srcB = srcA + 16;
  const bool hiF = ((g >> 1) & 1) != 0;

  const float lam = tanhf(log1pf(__expf(lambda_param[0])));
  const float L2E = 1.4426950408889634f;
  const float sc1 = 0.125f * L2E;
  const float sc2 = -lam * 0.125f * L2E;

  bf16x8 ones;
#pragma unroll
  for (int i = 0; i < 8; ++i) ones[i] = (__bf16)1.0f;

  bf16x8 qf[2][4];
#pragma unroll
  for (int fr = 0; fr < 2; ++fr) {
    int qrow = qt * 128 + w * 32 + fr * 16 + c;
    const __bf16* qbase = QK + (size_t)(b * S_ + qrow) * QKS_;
#pragma unroll
    for (int kk = 0; kk < 4; ++kk) {
      int d = kk * 32 + g * 8;
      const __bf16* src = (d < 64) ? (qbase + h * 64 + d)
                                   : (qbase + DV_ + h * 64 + (d - 64));
      float s = (d < 64) ? sc1 : sc2;
      bf16x8 raw = *reinterpret_cast<const bf16x8*>(src);
      bf16x8 ov;
#pragma unroll
      for (int i = 0; i < 8; ++i) ov[i] = (__bf16)((float)raw[i] * s);
      qf[fr][kk] = ov;
    }
  }

  f32x4 acc[2][4] = {};
  float mrow[2], lrow[2];
#pragma unroll
  for (int fr = 0; fr < 2; ++fr) { mrow[fr] = -1e30f; lrow[fr] = 0.f; }

  const int kt0 = half ? (qt + 1) : 0;
  const int kt1 = half ? (2 * qt + 2) : (qt + 1);

  auto stageK = [&](int p, int kt) {
#pragma unroll
    for (int j = 0; j < 4; ++j) {
      int row = w * 16 + j * 4 + (lane >> 4);
      int gc = (lane & 15) ^ fxor(row);
      int s = kt * 64 + row;
      const __bf16* kbase = QK + (size_t)(b * S_ + s) * QKS_ + 2048;
      const __bf16* src = (gc < 8) ? (kbase + h * 64 + gc * 8)
                                   : (kbase + DV_ + h * 64 + (gc - 8) * 8);
      gload_lds16(src, &Ks[p][(w * 16 + j * 4) * 128]);
    }
  };
  auto loadV = [&](int kt, bf16x8* vv) {
#pragma unroll
    for (int j = 0; j < 2; ++j) {
      int flat = tid + j * 256;
      int kv = flat >> 3;
      int d = (flat & 7) * 8;
      vv[j] = *reinterpret_cast<const bf16x8*>(
          V + (size_t)(b * S_ + kt * 64 + kv) * DV_ + h * 64 + d);
    }
  };
  auto scatterV = [&](int p, const bf16x8* vv) {
    char* VsB = (char*)Vs[p];
#pragma unroll
    for (int j = 0; j < 2; ++j) {
      int flat = tid + j * 256;
      int kv = flat >> 3;
      int d = (flat & 7) * 8;
#pragma unroll
      for (int i = 0; i < 8; ++i)
        *reinterpret_cast<__bf16*>(VsB + swz(d + i, kv * 2, 128)) = vv[j][i];
    }
  };

  {
    stageK(0, kt0);
    bf16x8 vv[2];
    loadV(kt0, vv);
    scatterV(0, vv);
    __syncthreads();
  }

  for (int kt = kt0; kt < kt1; ++kt) {
    const int p = (kt - kt0) & 1;
    const bool pre = (kt + 1 < kt1);
    bf16x8 vv[2];
    if (pre) {
      stageK(p ^ 1, kt + 1);
      loadV(kt + 1, vv);
    }

    f32x4 sc[2][4] = {};
    char* KsB = (char*)Ks[p];
    __builtin_amdgcn_s_setprio(1);
#pragma unroll
    for (int f = 0; f < 4; ++f)
#pragma unroll
      for (int kk = 0; kk < 4; ++kk) {
        bf16x8 kf = *reinterpret_cast<const bf16x8*>(
            KsB + swz(f * 16 + c, (kk * 32 + g * 8) * 2, 256));
        sc[0][f] = __builtin_amdgcn_mfma_f32_16x16x32_bf16(kf, qf[0][kk], sc[0][f], 0, 0, 0);
        sc[1][f] = __builtin_amdgcn_mfma_f32_16x16x32_bf16(kf, qf[1][kk], sc[1][f], 0, 0, 0);
      }
    __builtin_amdgcn_s_setprio(0);

    char* VsB = (char*)Vs[p];
    bf16x8 vfr[2][4];
#pragma unroll
    for (int kc = 0; kc < 2; ++kc)
#pragma unroll
      for (int n = 0; n < 4; ++n)
        vfr[kc][n] = *reinterpret_cast<const bf16x8*>(
            VsB + swz(n * 16 + c, (kc * 32 + g * 8) * 2, 128));

    const int dz = kt - 2 * qt;
#pragma unroll
    for (int fr = 0; fr < 2; ++fr) {
      const int wq = w * 32 + fr * 16 + c;
      float pmax = NEG_INF;
      if (dz >= 0) {
#pragma unroll
        for (int f = 0; f < 4; ++f)
#pragma unroll
          for (int r = 0; r < 4; ++r) {
            float s = sc[fr][f][r];
            if (dz * 64 + f * 16 + g * 4 + r > wq) s = NEG_INF;
            sc[fr][f][r] = s;
            pmax = fmaxf(pmax, s);
          }
      } else {
#pragma unroll
        for (int f = 0; f < 4; ++f)
#pragma unroll
          for (int r = 0; r < 4; ++r)
            pmax = fmaxf(pmax, sc[fr][f][r]);
      }

      if (!__all(pmax - mrow[fr] <= 8.0f)) {
        pmax = fmaxf(pmax, __shfl_xor(pmax, 16, 64));
        pmax = fmaxf(pmax, __shfl_xor(pmax, 32, 64));
        float mnew = fmaxf(mrow[fr], pmax);
        float pscl = __builtin_amdgcn_exp2f(mrow[fr] - mnew);
        mrow[fr] = mnew;
        lrow[fr] *= pscl;
#pragma unroll
        for (int n = 0; n < 4; ++n)
#pragma unroll
          for (int r = 0; r < 4; ++r)
            acc[fr][n][r] *= pscl;
      }

#pragma unroll
      for (int f = 0; f < 4; ++f)
#pragma unroll
        for (int r = 0; r < 4; ++r)
          sc[fr][f][r] = __builtin_amdgcn_exp2f(sc[fr][f][r] - mrow[fr]);

      unsigned int pk[4][2];
#pragma unroll
      for (int f = 0; f < 4; ++f) {
        pk[f][0] = pk2(sc[fr][f][0], sc[fr][f][1]);
        pk[f][1] = pk2(sc[fr][f][2], sc[fr][f][3]);
      }

      f32x4 rs = {};
      __builtin_amdgcn_s_setprio(1);
#pragma unroll
      for (int kc = 0; kc < 2; ++kc) {
        const int fA = kc * 2, fB = kc * 2 + 1;
        unsigned int a0 = __shfl((int)pk[fA][0], srcA, 64);
        unsigned int a1 = __shfl((int)pk[fA][1], srcA, 64);
        unsigned int a2 = __shfl((int)pk[fA][0], srcB, 64);
        unsigned int a3 = __shfl((int)pk[fA][1], srcB, 64);
        unsigned int b0 = __shfl((int)pk[fB][0], srcA, 64);
        unsigned int b1 = __shfl((int)pk[fB][1], srcA, 64);
        unsigned int b2 = __shfl((int)pk[fB][0], srcB, 64);
        unsigned int b3 = __shfl((int)pk[fB][1], srcB, 64);
        union { unsigned int u[4]; bf16x8 v; } pu;
        pu.u[0] = hiF ? b0 : a0;
        pu.u[1] = hiF ? b1 : a1;
        pu.u[2] = hiF ? b2 : a2;
        pu.u[3] = hiF ? b3 : a3;
        rs = __builtin_amdgcn_mfma_f32_16x16x32_bf16(ones, pu.v, rs, 0, 0, 0);
#pragma unroll
        for (int n = 0; n < 4; ++n)
          acc[fr][n] = __builtin_amdgcn_mfma_f32_16x16x32_bf16(vfr[kc][n], pu.v, acc[fr][n], 0, 0, 0);
      }
      __builtin_amdgcn_s_setprio(0);
      lrow[fr] += rs[0];
    }

    if (pre) scatterV(p ^ 1, vv);
    __syncthreads();
  }

  __bf16* Op = half ? OpB : OpA;
#pragma unroll
  for (int fr = 0; fr < 2; ++fr) {
    int q = qt * 128 + w * 32 + fr * 16 + c;
#pragma unroll
    for (int n = 0; n < 4; ++n)
#pragma unroll
      for (int r = 0; r < 4; ++r) {
        int d = n * 16 + g * 4 + r;
        Op[((size_t)bh * 64 + d) * S_ + q] = (__bf16)acc[fr][n][r];
      }
    if (g == 0) {
      float2 v;
      v.x = mrow[fr];
      v.y = lrow[fr];
      *reinterpret_cast<float2*>(&ml[((size_t)(half * 32 + bh) * S_ + q) * 2]) = v;
    }
  }
}

// ---------------- transpose-merge of the two KV halves ----------------

__global__ __launch_bounds__(256) void merge_halves(const __bf16* __restrict__ OpA,
                                                    const __bf16* __restrict__ OpB,
                                                    const float* __restrict__ ml,
                                                    __bf16* __restrict__ AO) {
  __shared__ __bf16 tile[64][72];
  __shared__ float wAB[64][2];
  const int bh = blockIdx.y;
  const int q0 = blockIdx.x * 64;
  const int b = bh >> 4, h = bh & 15;
  const int t = threadIdx.x;

  if (t < 64) {
    float2 a2 = *reinterpret_cast<const float2*>(&ml[((size_t)bh * S_ + q0 + t) * 2]);
    float2 b2 = *reinterpret_cast<const float2*>(&ml[((size_t)(32 + bh) * S_ + q0 + t) * 2]);
    float m = fmaxf(a2.x, b2.x);
    float wA = __builtin_amdgcn_exp2f(a2.x - m);
    float wB = __builtin_amdgcn_exp2f(b2.x - m);
    float inv = 1.0f / (a2.y * wA + b2.y * wB);
    wAB[t][0] = wA * inv;
    wAB[t][1] = wB * inv;
  }
  __syncthreads();

#pragma unroll
  for (int i = 0; i < 2; ++i) {
    int d = (t >> 3) + i * 32;
    int qc = (t & 7) * 8;
    size_t base = ((size_t)bh * 64 + d) * S_ + q0 + qc;
    bf16x8 oa = *reinterpret_cast<const bf16x8*>(OpA + base);
    bf16x8 ob = *reinterpret_cast<const bf16x8*>(OpB + base);
#pragma unroll
    for (int j = 0; j < 8; ++j)
      tile[d][qc + j] = (__bf16)((float)oa[j] * wAB[qc + j][0] + (float)ob[j] * wAB[qc + j][1]);
  }
  __syncthreads();

#pragma unroll
  for (int i = 0; i < 2; ++i) {
    int ql = (t >> 3) + i * 32;
    int dc = (t & 7) * 8;
    bf16x8 o;
#pragma unroll
    for (int j = 0; j < 8; ++j) o[j] = tile[dc + j][ql];
    *reinterpret_cast<bf16x8*>(AO + (size_t)(b * S_ + q0 + ql) * DV_ + h * 64 + dc) = o;
  }
}

// ---------------- launch ----------------

extern "C" void kernel_launch(void* const* d_in, const int* in_sizes, int n_in,
                              void* d_out, int out_size, void* d_ws, size_t ws_size,
                              hipStream_t stream) {
  const float* hidden = (const float*)d_in[0];
  const float* Wq = (const float*)d_in[2];
  const float* Wk = (const float*)d_in[3];
  const float* Wv = (const float*)d_in[4];
  const float* Wo = (const float*)d_in[5];
  const float* lambda_param = (const float*)d_in[6];
  float* out = (float*)d_out;

  char* ws = (char*)d_ws;
  size_t off = 0;
  auto alloc = [&](size_t bytes) {
    void* p = ws + off;
    off += (bytes + 255) & ~(size_t)255;
    return p;
  };
  const int M = B_ * S_;                                   // 4096
  __bf16* hidb = (__bf16*)alloc((size_t)M * H_ * 2);       // 16 MB
  __bf16* TB   = (__bf16*)alloc((size_t)QKS_ * H_ * 2);    // 16 MB
  __bf16* QKa  = (__bf16*)alloc((size_t)M * QKS_ * 2);     // 32 MB fused [q_all|k_all]
  __bf16* Va   = (__bf16*)((char*)TB + 4u * 1024 * 1024);  // 8 MB nested after WvT
  __bf16* AO   = Va;                                       // merged attn out (Va dead by then)
  float*  mlb  = (float*)((char*)TB + 12u * 1024 * 1024);  // 1 MB (m,l) partials
  __bf16* OpA  = hidb;                                     // 8 MB O^T partial (half 0)
  __bf16* OpB  = hidb + (size_t)M * DV_;                   // 8 MB O^T partial (half 1)
  (void)ws_size; (void)in_sizes; (void)n_in; (void)out_size;

  int nh = M * H_;
  cast_hidden<<<nh / (256 * 8), 256, 0, stream>>>(hidden, hidb, nh);

  // fused QK GEMM (256^2 8-phase): grid 16x16 = 256 blocks = 1/CU
  transpose_cast2<<<dim3(DQ_ / 32, H_ / 32, 2), 256, 0, stream>>>(
      Wq, TB, Wk, TB + (size_t)DQ_ * H_, H_, DQ_);
  gemm256<__bf16><<<dim3(QKS_ / 256, M / 256), 512, 0, stream>>>(hidb, TB, QKa, M, QKS_, H_);

  // V GEMM (128^2, full-width 256-block grid)
  transpose_cast<<<dim3(DV_ / 32, H_ / 32), 256, 0, stream>>>(Wv, TB, H_, DV_);
  gemm_bt<__bf16><<<dim3(DV_ / 128, M / 128), 256, 0, stream>>>(hidb, TB, Va, M, DV_, H_);

  // attention: swapped-QK reg-P, KV-split halves, balanced qt; O^T partials
  diffattn<<<dim3(S_ / 128, B_ * NH_ * 2), 256, 0, stream>>>(QKa, Va, OpA, OpB, mlb, lambda_param);

  // Wo transpose BEFORE merge (TB base, disjoint from AO at TB+4MB)
  transpose_cast<<<dim3(H_ / 32, DV_ / 32), 256, 0, stream>>>(Wo, TB, DV_, H_);
  // transpose-merge: Op^T -> AO (row-major)
  merge_halves<<<dim3(S_ / 64, B_ * NH_), 256, 0, stream>>>(OpA, OpB, mlb, AO);

  // out = AO @ Wo (f32 output), 256^2 8-phase, 8x16 = 128 blocks (single round)
  gemm256<float><<<dim3(H_ / 256, M / 256), 512, 0, stream>>>(AO, TB, out, M, H_, DV_);
}

// Round 18
// 235.333 us; speedup vs baseline: 1.0311x; 1.0311x over previous
//
#include <hip/hip_runtime.h>
#include <hip/hip_bf16.h>

#define B_ 2
#define S_ 2048
#define H_ 2048
#define NH_ 16
#define HD_ 64
#define DQ_ 2048   // 2*NH*HD
#define DV_ 1024   // NH*HD
#define QKS_ 4096  // fused QK row stride

using bf16x8 = __attribute__((ext_vector_type(8))) __bf16;
using f32x4  = __attribute__((ext_vector_type(4))) float;

typedef __attribute__((address_space(1))) unsigned int u32g;
typedef __attribute__((address_space(3))) unsigned int u32l;

__device__ __forceinline__ void gload_lds16(const __bf16* g, __bf16* l) {
  __builtin_amdgcn_global_load_lds((u32g*)g, (u32l*)l, 16, 0, 0);
}

// XOR-swizzle, 256B rows (16 chunks of 16B): involution, write+read identical.
__device__ __forceinline__ int swz(int row, int colb, int strideB) {
  return row * strideB + (colb ^ (((row ^ (row >> 3)) & 7) << 4));
}
__device__ __forceinline__ int fxor(int row) { return (row ^ (row >> 3)) & 7; }

__device__ __forceinline__ unsigned int pk2(float a, float b) {
  __bf16 ba = (__bf16)a, bb = (__bf16)b;
  unsigned short ua, ub;
  __builtin_memcpy(&ua, &ba, 2);
  __builtin_memcpy(&ub, &bb, 2);
  return (unsigned int)ua | ((unsigned int)ub << 16);
}

// ---------------- prep kernels ----------------

__global__ __launch_bounds__(256) void cast_hidden(const float* __restrict__ in,
                                                   __bf16* __restrict__ out, int n) {
  int i = (blockIdx.x * 256 + threadIdx.x) * 8;
  if (i >= n) return;
  float4 a = *reinterpret_cast<const float4*>(in + i);
  float4 b = *reinterpret_cast<const float4*>(in + i + 4);
  bf16x8 o;
  o[0] = (__bf16)a.x; o[1] = (__bf16)a.y; o[2] = (__bf16)a.z; o[3] = (__bf16)a.w;
  o[4] = (__bf16)b.x; o[5] = (__bf16)b.y; o[6] = (__bf16)b.z; o[7] = (__bf16)b.w;
  *reinterpret_cast<bf16x8*>(out + i) = o;
}

// in: R x C f32 row-major  ->  out: C x R bf16 row-major
__global__ __launch_bounds__(256) void transpose_cast(const float* __restrict__ in,
                                                      __bf16* __restrict__ out, int R, int C) {
  __shared__ float tile[32][33];
  int tx = threadIdx.x & 31, ty = threadIdx.x >> 5;
  int c0 = blockIdx.x * 32, r0 = blockIdx.y * 32;
  for (int i = 0; i < 32; i += 8)
    tile[ty + i][tx] = in[(size_t)(r0 + ty + i) * C + c0 + tx];
  __syncthreads();
  for (int i = 0; i < 32; i += 8)
    out[(size_t)(c0 + ty + i) * R + r0 + tx] = (__bf16)tile[tx][ty + i];
}

// dual transpose (z selects job): one launch for Wq+Wk
__global__ __launch_bounds__(256) void transpose_cast2(const float* __restrict__ in0,
                                                       __bf16* __restrict__ out0,
                                                       const float* __restrict__ in1,
                                                       __bf16* __restrict__ out1,
                                                       int R, int C) {
  __shared__ float tile[32][33];
  const float* in = blockIdx.z ? in1 : in0;
  __bf16* out = blockIdx.z ? out1 : out0;
  int tx = threadIdx.x & 31, ty = threadIdx.x >> 5;
  int c0 = blockIdx.x * 32, r0 = blockIdx.y * 32;
  for (int i = 0; i < 32; i += 8)
    tile[ty + i][tx] = in[(size_t)(r0 + ty + i) * C + c0 + tx];
  __syncthreads();
  for (int i = 0; i < 32; i += 8)
    out[(size_t)(c0 + ty + i) * R + r0 + tx] = (__bf16)tile[tx][ty + i];
}

// ------- GEMM: C[M][N] = A[M][K] * Bt[N][K]^T, 2-deep counted-vmcnt pipeline ----
// (V and O GEMMs; 128x128 tile keeps their grids full-machine: 256/512 blocks)

template <typename OutT>
__global__ __launch_bounds__(256) void gemm_bt(const __bf16* __restrict__ A,
                                               const __bf16* __restrict__ Bt,
                                               OutT* __restrict__ C,
                                               int M, int N, int K) {
  __shared__ __bf16 As[2][128 * 32];
  __shared__ __bf16 Bs[2][128 * 32];
  const int nx = gridDim.x;
  int id = blockIdx.y * nx + blockIdx.x;
  const int cpx = (nx * gridDim.y) >> 3;
  id = (id & 7) * cpx + (id >> 3);
  const int bm = id / nx, bn = id % nx;

  const int tid = threadIdx.x;
  const int wid = tid >> 6, lane = tid & 63;
  const int wm = wid >> 1, wn = wid & 1;
  const int g = lane >> 4, c = lane & 15;

  f32x4 acc[4][4] = {};
  const __bf16* Abase = A + (size_t)(bm * 128) * K;
  const __bf16* Bbase = Bt + (size_t)(bn * 128) * K;
  const int srow = wid * 16 + (lane >> 2);
  const int scol = (lane & 3) * 8;
  const int nk = K >> 5;

  auto stage = [&](int p, int kt) {
    int k0 = kt * 32;
    gload_lds16(Abase + (size_t)srow * K + k0 + scol,        &As[p][(wid * 16) * 32]);
    gload_lds16(Abase + (size_t)(srow + 64) * K + k0 + scol, &As[p][(64 + wid * 16) * 32]);
    gload_lds16(Bbase + (size_t)srow * K + k0 + scol,        &Bs[p][(wid * 16) * 32]);
    gload_lds16(Bbase + (size_t)(srow + 64) * K + k0 + scol, &Bs[p][(64 + wid * 16) * 32]);
  };

  stage(0, 0);
  stage(1, 1);

  for (int kt = 0; kt < nk; ++kt) {
    const int p = kt & 1;
    if (kt + 1 < nk) {
      asm volatile("s_waitcnt vmcnt(4)" ::: "memory");
    } else {
      asm volatile("s_waitcnt vmcnt(0)" ::: "memory");
    }
    __builtin_amdgcn_s_barrier();
    __builtin_amdgcn_sched_barrier(0);

    bf16x8 af[4], bfv[4];
#pragma unroll
    for (int i = 0; i < 4; ++i)
      af[i] = *reinterpret_cast<const bf16x8*>(&As[p][(wm * 64 + i * 16 + c) * 32 + g * 8]);
#pragma unroll
    for (int i = 0; i < 4; ++i)
      bfv[i] = *reinterpret_cast<const bf16x8*>(&Bs[p][(wn * 64 + i * 16 + c) * 32 + g * 8]);
#pragma unroll
    for (int m = 0; m < 4; ++m)
#pragma unroll
      for (int n = 0; n < 4; ++n)
        acc[m][n] = __builtin_amdgcn_mfma_f32_16x16x32_bf16(af[m], bfv[n], acc[m][n], 0, 0, 0);

    __builtin_amdgcn_sched_barrier(0);
    __builtin_amdgcn_s_barrier();
    if (kt + 2 < nk) stage(p, kt + 2);
  }

#pragma unroll
  for (int m = 0; m < 4; ++m)
#pragma unroll
    for (int n = 0; n < 4; ++n)
#pragma unroll
      for (int r = 0; r < 4; ++r) {
        int row = bm * 128 + wm * 64 + m * 16 + g * 4 + r;
        int col = bn * 128 + wn * 64 + n * 16 + c;
        float v = acc[m][n][r];
        if constexpr (sizeof(OutT) == 2)
          C[(size_t)row * N + col] = (OutT)(__bf16)v;
        else
          C[(size_t)row * N + col] = v;
      }
}

// ---- GEMM 256x256, 8 waves, BK=64, 8-phase counted-vmcnt schedule ----
// (verified R11; used ONLY for the QK GEMM whose 256-block grid fills the machine.
//  R17 lesson: at 128 blocks (O GEMM) half the CUs idle -> regression.)

template <typename OutT>
__global__ __launch_bounds__(512, 2) void gemm256(const __bf16* __restrict__ A,
                                                  const __bf16* __restrict__ Bt,
                                                  OutT* __restrict__ C,
                                                  int M, int N, int K) {
  __shared__ __bf16 As[2][256 * 64];
  __shared__ __bf16 Bs[2][256 * 64];
  const int nx = gridDim.x;
  int id = blockIdx.y * nx + blockIdx.x;
  const int cpx = (nx * gridDim.y) >> 3;
  id = (id & 7) * cpx + (id >> 3);
  const int bm = id / nx, bn = id % nx;

  const int tid = threadIdx.x;
  const int wid = tid >> 6, lane = tid & 63;
  const int wm = wid >> 2, wn = wid & 3;
  const int g = lane >> 4, c = lane & 15;

  f32x4 acc[8][4] = {};
  bf16x8 af[4][2];
  bf16x8 bfv[4][2];
  const __bf16* Abase = A + (size_t)(bm * 256) * K;
  const __bf16* Bbase = Bt + (size_t)(bn * 256) * K;
  const int niter = K >> 7;

  auto stageA = [&](int p, int half, int kt) {
#pragma unroll
    for (int j = 0; j < 2; ++j) {
      int row = half * 128 + j * 64 + wid * 8 + (lane >> 3);
      int gc = (lane & 7) ^ (row & 7);
      gload_lds16(Abase + (size_t)row * K + kt * 64 + gc * 8,
                  &As[p][(half * 128 + j * 64 + wid * 8) * 64]);
    }
  };
  auto stageB = [&](int p, int half, int kt) {
#pragma unroll
    for (int j = 0; j < 2; ++j) {
      int row = half * 128 + j * 64 + wid * 8 + (lane >> 3);
      int gc = (lane & 7) ^ (row & 7);
      gload_lds16(Bbase + (size_t)row * K + kt * 64 + gc * 8,
                  &Bs[p][(half * 128 + j * 64 + wid * 8) * 64]);
    }
  };
  auto readA = [&](int p, int m, int kk) -> bf16x8 {
    int row = wm * 128 + m * 16 + c;
    int ch = (kk * 4 + g) ^ (row & 7);
    return *reinterpret_cast<const bf16x8*>(&As[p][row * 64 + ch * 8]);
  };
  auto readB = [&](int p, int n, int kk) -> bf16x8 {
    int row = wn * 64 + n * 16 + c;
    int ch = (kk * 4 + g) ^ (row & 7);
    return *reinterpret_cast<const bf16x8*>(&Bs[p][row * 64 + ch * 8]);
  };
  auto quad = [&](int mb, int nb) {
    __builtin_amdgcn_s_setprio(1);
#pragma unroll
    for (int mi = 0; mi < 4; ++mi)
#pragma unroll
      for (int ni = 0; ni < 2; ++ni)
#pragma unroll
        for (int kk = 0; kk < 2; ++kk)
          acc[mb + mi][nb + ni] = __builtin_amdgcn_mfma_f32_16x16x32_bf16(
              af[mi][kk], bfv[nb + ni][kk], acc[mb + mi][nb + ni], 0, 0, 0);
    __builtin_amdgcn_s_setprio(0);
  };
#define BAR1_LGKM()  __builtin_amdgcn_s_barrier(); \
    asm volatile("s_waitcnt lgkmcnt(0)" ::: "memory"); \
    __builtin_amdgcn_sched_barrier(0)
#define BAR2()  __builtin_amdgcn_sched_barrier(0); __builtin_amdgcn_s_barrier()

  stageA(0, 0, 0); stageA(0, 1, 0);
  stageB(0, 0, 0); stageB(0, 1, 0);
  stageB(1, 0, 1); stageB(1, 1, 1);
  asm volatile("s_waitcnt vmcnt(0)" ::: "memory");
  __builtin_amdgcn_s_barrier();

  for (int i = 0; i < niter; ++i) {
    const int t1 = 2 * i + 1;
    const bool more = (i + 1 < niter);
    // ph1
#pragma unroll
    for (int mi = 0; mi < 4; ++mi) { af[mi][0] = readA(0, mi, 0); af[mi][1] = readA(0, mi, 1); }
#pragma unroll
    for (int ni = 0; ni < 2; ++ni) { bfv[ni][0] = readB(0, ni, 0); bfv[ni][1] = readB(0, ni, 1); }
    stageA(1, 0, t1);
    BAR1_LGKM(); quad(0, 0); BAR2();
    // ph2
#pragma unroll
    for (int ni = 2; ni < 4; ++ni) { bfv[ni][0] = readB(0, ni, 0); bfv[ni][1] = readB(0, ni, 1); }
    stageA(1, 1, t1);
    BAR1_LGKM(); quad(0, 2); BAR2();
    // ph3
#pragma unroll
    for (int mi = 0; mi < 4; ++mi) { af[mi][0] = readA(0, 4 + mi, 0); af[mi][1] = readA(0, 4 + mi, 1); }
    if (more) stageB(0, 0, t1 + 1);
    BAR1_LGKM(); quad(4, 0); BAR2();
    // ph4
    if (more) {
      stageB(0, 1, t1 + 1);
      asm volatile("s_waitcnt vmcnt(4)" ::: "memory");
    } else {
      asm volatile("s_waitcnt vmcnt(0)" ::: "memory");
    }
    __builtin_amdgcn_s_barrier();
    __builtin_amdgcn_sched_barrier(0);
    quad(4, 2); BAR2();
    // ph5
#pragma unroll
    for (int mi = 0; mi < 4; ++mi) { af[mi][0] = readA(1, mi, 0); af[mi][1] = readA(1, mi, 1); }
#pragma unroll
    for (int ni = 0; ni < 2; ++ni) { bfv[ni][0] = readB(1, ni, 0); bfv[ni][1] = readB(1, ni, 1); }
    if (more) stageA(0, 0, t1 + 1);
    BAR1_LGKM(); quad(0, 0); BAR2();
    // ph6
#pragma unroll
    for (int ni = 2; ni < 4; ++ni) { bfv[ni][0] = readB(1, ni, 0); bfv[ni][1] = readB(1, ni, 1); }
    if (more) stageA(0, 1, t1 + 1);
    BAR1_LGKM(); quad(0, 2); BAR2();
    // ph7
#pragma unroll
    for (int mi = 0; mi < 4; ++mi) { af[mi][0] = readA(1, 4 + mi, 0); af[mi][1] = readA(1, 4 + mi, 1); }
    if (more) stageB(1, 0, t1 + 2);
    BAR1_LGKM(); quad(4, 0); BAR2();
    // ph8
    if (more) {
      stageB(1, 1, t1 + 2);
      asm volatile("s_waitcnt vmcnt(4)" ::: "memory");
    } else {
      asm volatile("s_waitcnt vmcnt(0)" ::: "memory");
    }
    __builtin_amdgcn_s_barrier();
    __builtin_amdgcn_sched_barrier(0);
    quad(4, 2); BAR2();
  }
#undef BAR1_LGKM
#undef BAR2

#pragma unroll
  for (int m = 0; m < 8; ++m)
#pragma unroll
    for (int n = 0; n < 4; ++n)
#pragma unroll
      for (int r = 0; r < 4; ++r) {
        int row = bm * 256 + wm * 128 + m * 16 + g * 4 + r;
        int col = bn * 256 + wn * 64 + n * 16 + c;
        float v = acc[m][n][r];
        if constexpr (sizeof(OutT) == 2)
          C[(size_t)row * N + col] = (OutT)(__bf16)v;
        else
          C[(size_t)row * N + col] = v;
      }
}

// ------------- differential flash attention: swapped-QK, P in registers -----------
// (R16 measured-best, 80 us. UNCHANGED.)

__global__ __launch_bounds__(256, 2) void diffattn(const __bf16* __restrict__ QK,
                                                   const __bf16* __restrict__ V,
                                                   __bf16* __restrict__ OpA,
                                                   __bf16* __restrict__ OpB,
                                                   float* __restrict__ ml,
                                                   const float* __restrict__ lambda_param) {
  __shared__ __bf16 Ks[2][64 * 128];   // [kv][d] swizzled, 2x16KB
  __shared__ __bf16 Vs[2][64 * 64];    // [d][kv] (V^T) swizzled, 2x8KB

  const int y = blockIdx.y;
  const int qt = ((y >> 4) & 1) ? blockIdx.x : (gridDim.x - 1 - blockIdx.x);
  const int bh = y >> 1;
  const int half = y & 1;
  const int b = bh >> 4, h = bh & 15;
  const int tid = threadIdx.x;
  const int w = tid >> 6, lane = tid & 63;
  const int g = lane >> 4, c = lane & 15;
  const float NEG_INF = -__builtin_inff();

  const int srcA = c + 32 * (g & 1);
  const int srcB = srcA + 16;
  const bool hiF = ((g >> 1) & 1) != 0;

  const float lam = tanhf(log1pf(__expf(lambda_param[0])));
  const float L2E = 1.4426950408889634f;
  const float sc1 = 0.125f * L2E;
  const float sc2 = -lam * 0.125f * L2E;

  bf16x8 ones;
#pragma unroll
  for (int i = 0; i < 8; ++i) ones[i] = (__bf16)1.0f;

  bf16x8 qf[2][4];
#pragma unroll
  for (int fr = 0; fr < 2; ++fr) {
    int qrow = qt * 128 + w * 32 + fr * 16 + c;
    const __bf16* qbase = QK + (size_t)(b * S_ + qrow) * QKS_;
#pragma unroll
    for (int kk = 0; kk < 4; ++kk) {
      int d = kk * 32 + g * 8;
      const __bf16* src = (d < 64) ? (qbase + h * 64 + d)
                                   : (qbase + DV_ + h * 64 + (d - 64));
      float s = (d < 64) ? sc1 : sc2;
      bf16x8 raw = *reinterpret_cast<const bf16x8*>(src);
      bf16x8 ov;
#pragma unroll
      for (int i = 0; i < 8; ++i) ov[i] = (__bf16)((float)raw[i] * s);
      qf[fr][kk] = ov;
    }
  }

  f32x4 acc[2][4] = {};
  float mrow[2], lrow[2];
#pragma unroll
  for (int fr = 0; fr < 2; ++fr) { mrow[fr] = -1e30f; lrow[fr] = 0.f; }

  const int kt0 = half ? (qt + 1) : 0;
  const int kt1 = half ? (2 * qt + 2) : (qt + 1);

  auto stageK = [&](int p, int kt) {
#pragma unroll
    for (int j = 0; j < 4; ++j) {
      int row = w * 16 + j * 4 + (lane >> 4);
      int gc = (lane & 15) ^ fxor(row);
      int s = kt * 64 + row;
      const __bf16* kbase = QK + (size_t)(b * S_ + s) * QKS_ + 2048;
      const __bf16* src = (gc < 8) ? (kbase + h * 64 + gc * 8)
                                   : (kbase + DV_ + h * 64 + (gc - 8) * 8);
      gload_lds16(src, &Ks[p][(w * 16 + j * 4) * 128]);
    }
  };
  auto loadV = [&](int kt, bf16x8* vv) {
#pragma unroll
    for (int j = 0; j < 2; ++j) {
      int flat = tid + j * 256;
      int kv = flat >> 3;
      int d = (flat & 7) * 8;
      vv[j] = *reinterpret_cast<const bf16x8*>(
          V + (size_t)(b * S_ + kt * 64 + kv) * DV_ + h * 64 + d);
    }
  };
  auto scatterV = [&](int p, const bf16x8* vv) {
    char* VsB = (char*)Vs[p];
#pragma unroll
    for (int j = 0; j < 2; ++j) {
      int flat = tid + j * 256;
      int kv = flat >> 3;
      int d = (flat & 7) * 8;
#pragma unroll
      for (int i = 0; i < 8; ++i)
        *reinterpret_cast<__bf16*>(VsB + swz(d + i, kv * 2, 128)) = vv[j][i];
    }
  };

  {
    stageK(0, kt0);
    bf16x8 vv[2];
    loadV(kt0, vv);
    scatterV(0, vv);
    __syncthreads();
  }

  for (int kt = kt0; kt < kt1; ++kt) {
    const int p = (kt - kt0) & 1;
    const bool pre = (kt + 1 < kt1);
    bf16x8 vv[2];
    if (pre) {
      stageK(p ^ 1, kt + 1);
      loadV(kt + 1, vv);
    }

    f32x4 sc[2][4] = {};
    char* KsB = (char*)Ks[p];
    __builtin_amdgcn_s_setprio(1);
#pragma unroll
    for (int f = 0; f < 4; ++f)
#pragma unroll
      for (int kk = 0; kk < 4; ++kk) {
        bf16x8 kf = *reinterpret_cast<const bf16x8*>(
            KsB + swz(f * 16 + c, (kk * 32 + g * 8) * 2, 256));
        sc[0][f] = __builtin_amdgcn_mfma_f32_16x16x32_bf16(kf, qf[0][kk], sc[0][f], 0, 0, 0);
        sc[1][f] = __builtin_amdgcn_mfma_f32_16x16x32_bf16(kf, qf[1][kk], sc[1][f], 0, 0, 0);
      }
    __builtin_amdgcn_s_setprio(0);

    char* VsB = (char*)Vs[p];
    bf16x8 vfr[2][4];
#pragma unroll
    for (int kc = 0; kc < 2; ++kc)
#pragma unroll
      for (int n = 0; n < 4; ++n)
        vfr[kc][n] = *reinterpret_cast<const bf16x8*>(
            VsB + swz(n * 16 + c, (kc * 32 + g * 8) * 2, 128));

    const int dz = kt - 2 * qt;
#pragma unroll
    for (int fr = 0; fr < 2; ++fr) {
      const int wq = w * 32 + fr * 16 + c;
      float pmax = NEG_INF;
      if (dz >= 0) {
#pragma unroll
        for (int f = 0; f < 4; ++f)
#pragma unroll
          for (int r = 0; r < 4; ++r) {
            float s = sc[fr][f][r];
            if (dz * 64 + f * 16 + g * 4 + r > wq) s = NEG_INF;
            sc[fr][f][r] = s;
            pmax = fmaxf(pmax, s);
          }
      } else {
#pragma unroll
        for (int f = 0; f < 4; ++f)
#pragma unroll
          for (int r = 0; r < 4; ++r)
            pmax = fmaxf(pmax, sc[fr][f][r]);
      }

      if (!__all(pmax - mrow[fr] <= 8.0f)) {
        pmax = fmaxf(pmax, __shfl_xor(pmax, 16, 64));
        pmax = fmaxf(pmax, __shfl_xor(pmax, 32, 64));
        float mnew = fmaxf(mrow[fr], pmax);
        float pscl = __builtin_amdgcn_exp2f(mrow[fr] - mnew);
        mrow[fr] = mnew;
        lrow[fr] *= pscl;
#pragma unroll
        for (int n = 0; n < 4; ++n)
#pragma unroll
          for (int r = 0; r < 4; ++r)
            acc[fr][n][r] *= pscl;
      }

#pragma unroll
      for (int f = 0; f < 4; ++f)
#pragma unroll
        for (int r = 0; r < 4; ++r)
          sc[fr][f][r] = __builtin_amdgcn_exp2f(sc[fr][f][r] - mrow[fr]);

      unsigned int pk[4][2];
#pragma unroll
      for (int f = 0; f < 4; ++f) {
        pk[f][0] = pk2(sc[fr][f][0], sc[fr][f][1]);
        pk[f][1] = pk2(sc[fr][f][2], sc[fr][f][3]);
      }

      f32x4 rs = {};
      __builtin_amdgcn_s_setprio(1);
#pragma unroll
      for (int kc = 0; kc < 2; ++kc) {
        const int fA = kc * 2, fB = kc * 2 + 1;
        unsigned int a0 = __shfl((int)pk[fA][0], srcA, 64);
        unsigned int a1 = __shfl((int)pk[fA][1], srcA, 64);
        unsigned int a2 = __shfl((int)pk[fA][0], srcB, 64);
        unsigned int a3 = __shfl((int)pk[fA][1], srcB, 64);
        unsigned int b0 = __shfl((int)pk[fB][0], srcA, 64);
        unsigned int b1 = __shfl((int)pk[fB][1], srcA, 64);
        unsigned int b2 = __shfl((int)pk[fB][0], srcB, 64);
        unsigned int b3 = __shfl((int)pk[fB][1], srcB, 64);
        union { unsigned int u[4]; bf16x8 v; } pu;
        pu.u[0] = hiF ? b0 : a0;
        pu.u[1] = hiF ? b1 : a1;
        pu.u[2] = hiF ? b2 : a2;
        pu.u[3] = hiF ? b3 : a3;
        rs = __builtin_amdgcn_mfma_f32_16x16x32_bf16(ones, pu.v, rs, 0, 0, 0);
#pragma unroll
        for (int n = 0; n < 4; ++n)
          acc[fr][n] = __builtin_amdgcn_mfma_f32_16x16x32_bf16(vfr[kc][n], pu.v, acc[fr][n], 0, 0, 0);
      }
      __builtin_amdgcn_s_setprio(0);
      lrow[fr] += rs[0];
    }

    if (pre) scatterV(p ^ 1, vv);
    __syncthreads();
  }

  __bf16* Op = half ? OpB : OpA;
#pragma unroll
  for (int fr = 0; fr < 2; ++fr) {
    int q = qt * 128 + w * 32 + fr * 16 + c;
#pragma unroll
    for (int n = 0; n < 4; ++n)
#pragma unroll
      for (int r = 0; r < 4; ++r) {
        int d = n * 16 + g * 4 + r;
        Op[((size_t)bh * 64 + d) * S_ + q] = (__bf16)acc[fr][n][r];
      }
    if (g == 0) {
      float2 v;
      v.x = mrow[fr];
      v.y = lrow[fr];
      *reinterpret_cast<float2*>(&ml[((size_t)(half * 32 + bh) * S_ + q) * 2]) = v;
    }
  }
}

// ---------------- transpose-merge of the two KV halves ----------------

__global__ __launch_bounds__(256) void merge_halves(const __bf16* __restrict__ OpA,
                                                    const __bf16* __restrict__ OpB,
                                                    const float* __restrict__ ml,
                                                    __bf16* __restrict__ AO) {
  __shared__ __bf16 tile[64][72];
  __shared__ float wAB[64][2];
  const int bh = blockIdx.y;
  const int q0 = blockIdx.x * 64;
  const int b = bh >> 4, h = bh & 15;
  const int t = threadIdx.x;

  if (t < 64) {
    float2 a2 = *reinterpret_cast<const float2*>(&ml[((size_t)bh * S_ + q0 + t) * 2]);
    float2 b2 = *reinterpret_cast<const float2*>(&ml[((size_t)(32 + bh) * S_ + q0 + t) * 2]);
    float m = fmaxf(a2.x, b2.x);
    float wA = __builtin_amdgcn_exp2f(a2.x - m);
    float wB = __builtin_amdgcn_exp2f(b2.x - m);
    float inv = 1.0f / (a2.y * wA + b2.y * wB);
    wAB[t][0] = wA * inv;
    wAB[t][1] = wB * inv;
  }
  __syncthreads();

#pragma unroll
  for (int i = 0; i < 2; ++i) {
    int d = (t >> 3) + i * 32;
    int qc = (t & 7) * 8;
    size_t base = ((size_t)bh * 64 + d) * S_ + q0 + qc;
    bf16x8 oa = *reinterpret_cast<const bf16x8*>(OpA + base);
    bf16x8 ob = *reinterpret_cast<const bf16x8*>(OpB + base);
#pragma unroll
    for (int j = 0; j < 8; ++j)
      tile[d][qc + j] = (__bf16)((float)oa[j] * wAB[qc + j][0] + (float)ob[j] * wAB[qc + j][1]);
  }
  __syncthreads();

#pragma unroll
  for (int i = 0; i < 2; ++i) {
    int ql = (t >> 3) + i * 32;
    int dc = (t & 7) * 8;
    bf16x8 o;
#pragma unroll
    for (int j = 0; j < 8; ++j) o[j] = tile[dc + j][ql];
    *reinterpret_cast<bf16x8*>(AO + (size_t)(b * S_ + q0 + ql) * DV_ + h * 64 + dc) = o;
  }
}

// ---------------- launch ----------------

extern "C" void kernel_launch(void* const* d_in, const int* in_sizes, int n_in,
                              void* d_out, int out_size, void* d_ws, size_t ws_size,
                              hipStream_t stream) {
  const float* hidden = (const float*)d_in[0];
  const float* Wq = (const float*)d_in[2];
  const float* Wk = (const float*)d_in[3];
  const float* Wv = (const float*)d_in[4];
  const float* Wo = (const float*)d_in[5];
  const float* lambda_param = (const float*)d_in[6];
  float* out = (float*)d_out;

  char* ws = (char*)d_ws;
  size_t off = 0;
  auto alloc = [&](size_t bytes) {
    void* p = ws + off;
    off += (bytes + 255) & ~(size_t)255;
    return p;
  };
  const int M = B_ * S_;                                   // 4096
  __bf16* hidb = (__bf16*)alloc((size_t)M * H_ * 2);       // 16 MB
  __bf16* TB   = (__bf16*)alloc((size_t)QKS_ * H_ * 2);    // 16 MB
  __bf16* QKa  = (__bf16*)alloc((size_t)M * QKS_ * 2);     // 32 MB fused [q_all|k_all]
  __bf16* Va   = (__bf16*)((char*)TB + 4u * 1024 * 1024);  // 8 MB nested after WvT
  __bf16* AO   = Va;                                       // merged attn out (Va dead by then)
  float*  mlb  = (float*)((char*)TB + 12u * 1024 * 1024);  // 1 MB (m,l) partials
  __bf16* OpA  = hidb;                                     // 8 MB O^T partial (half 0)
  __bf16* OpB  = hidb + (size_t)M * DV_;                   // 8 MB O^T partial (half 1)
  (void)ws_size; (void)in_sizes; (void)n_in; (void)out_size;

  int nh = M * H_;
  cast_hidden<<<nh / (256 * 8), 256, 0, stream>>>(hidden, hidb, nh);

  // fused QK GEMM (256^2 8-phase): grid 16x16 = 256 blocks = 1/CU
  transpose_cast2<<<dim3(DQ_ / 32, H_ / 32, 2), 256, 0, stream>>>(
      Wq, TB, Wk, TB + (size_t)DQ_ * H_, H_, DQ_);
  gemm256<__bf16><<<dim3(QKS_ / 256, M / 256), 512, 0, stream>>>(hidb, TB, QKa, M, QKS_, H_);

  // V GEMM (128^2, full-width 256-block grid)
  transpose_cast<<<dim3(DV_ / 32, H_ / 32), 256, 0, stream>>>(Wv, TB, H_, DV_);
  gemm_bt<__bf16><<<dim3(DV_ / 128, M / 128), 256, 0, stream>>>(hidb, TB, Va, M, DV_, H_);

  // attention: swapped-QK reg-P, KV-split halves, balanced qt; O^T partials
  diffattn<<<dim3(S_ / 128, B_ * NH_ * 2), 256, 0, stream>>>(QKa, Va, OpA, OpB, mlb, lambda_param);

  // Wo transpose BEFORE merge (TB base, disjoint from AO at TB+4MB)
  transpose_cast<<<dim3(H_ / 32, DV_ / 32), 256, 0, stream>>>(Wo, TB, DV_, H_);
  // transpose-merge: Op^T -> AO (row-major)
  merge_halves<<<dim3(S_ / 64, B_ * NH_), 256, 0, stream>>>(OpA, OpB, mlb, AO);

  // out = AO @ Wo (f32 output), 128^2 gemm_bt: 16x32 = 512 blocks (full machine)
  gemm_bt<float><<<dim3(H_ / 128, M / 128), 256, 0, stream>>>(AO, TB, out, M, H_, DV_);
}